// Round 1
// baseline (261.654 us; speedup 1.0000x reference)
//
#include <hip/hip_runtime.h>
#include <cmath>

#define NB    64
#define TENC  1024
#define DENC  512
#define QDIM  1024
#define HDIM  256
#define NM    5
#define EPSF  1e-5f
#define SSPLIT 16
#define TCH   (TENC / SSPLIT)   // 64 t-rows per context block

// ---------------------------------------------------------------------------
// Kernel 1: per-batch front end.
//   h = relu(q @ W1 + b1)            (1024 -> 256)
//   params = h @ W2 + b2             (256 -> 15)
//   w = softmax(params[0:5]) + eps
//   sigma = softplus(params[5:10]) + eps
//   mu = mu_prev + softplus(params[10:15])
//   alpha[t] = F(t+1.5) - F(t+0.5),  F(j) = sum_m w_m / (1 + sigmoid((mu_m-j)/sigma_m))
//   alpha: ==0 -> eps, then mask -> 0; written to d_out's alpha region.
// One block per batch row, 256 threads.
// ---------------------------------------------------------------------------
__global__ __launch_bounds__(256) void mol_front(
    const float* __restrict__ q,        // B x 1024
    const float* __restrict__ W1,       // 1024 x 256 (row-major)
    const float* __restrict__ b1,       // 256
    const float* __restrict__ W2,       // 256 x 15
    const float* __restrict__ b2,       // 15
    const float* __restrict__ mu_prev,  // B x 5
    const unsigned char* __restrict__ mask, // B x 1024 (bool, 1 byte)
    float* __restrict__ alpha_out)      // B x 1024
{
    __shared__ float  q_lds[QDIM];
    __shared__ float4 part[4][64];      // split-K partials
    __shared__ float  h_lds[HDIM];
    __shared__ float  p_lds[16];
    __shared__ float  stats[16];        // w[5], sigma[5], mu[5]

    const int b   = blockIdx.x;
    const int tid = threadIdx.x;

    // stage q row (4 KB) into LDS, float4-coalesced
    ((float4*)q_lds)[tid] = ((const float4*)(q + (size_t)b * QDIM))[tid];
    __syncthreads();

    // h = relu(q @ W1 + b1): thread = (g = k-group 0..3, c = output float4 0..63)
    const int g = tid >> 6;
    const int c = tid & 63;
    {
        const float4* W1v = (const float4*)W1;   // [k][64] float4
        float4 acc = make_float4(0.f, 0.f, 0.f, 0.f);
        const int k0 = g << 8;
        #pragma unroll 4
        for (int k = 0; k < 256; ++k) {
            const float  qk = q_lds[k0 + k];                    // wave-broadcast
            const float4 wv = W1v[(size_t)(k0 + k) * 64 + c];   // 1KB/wave coalesced
            acc.x = fmaf(qk, wv.x, acc.x);
            acc.y = fmaf(qk, wv.y, acc.y);
            acc.z = fmaf(qk, wv.z, acc.z);
            acc.w = fmaf(qk, wv.w, acc.w);
        }
        part[g][c] = acc;
    }
    __syncthreads();

    if (tid < 64) {
        const float4 s0 = part[0][tid], s1 = part[1][tid];
        const float4 s2 = part[2][tid], s3 = part[3][tid];
        const float4 bb = ((const float4*)b1)[tid];
        float4 h;
        h.x = fmaxf(s0.x + s1.x + s2.x + s3.x + bb.x, 0.f);
        h.y = fmaxf(s0.y + s1.y + s2.y + s3.y + bb.y, 0.f);
        h.z = fmaxf(s0.z + s1.z + s2.z + s3.z + bb.z, 0.f);
        h.w = fmaxf(s0.w + s1.w + s2.w + s3.w + bb.w, 0.f);
        ((float4*)h_lds)[tid] = h;
    }
    __syncthreads();

    // params = h @ W2 + b2 (15 outputs; W2 is 15 KB, L1/L2-resident)
    if (tid < 15) {
        float acc = b2[tid];
        #pragma unroll 8
        for (int i = 0; i < HDIM; ++i) acc = fmaf(h_lds[i], W2[i * 15 + tid], acc);
        p_lds[tid] = acc;
    }
    __syncthreads();

    if (tid == 0) {
        // softmax over p[0:5]
        float mx = p_lds[0];
        #pragma unroll
        for (int m = 1; m < NM; ++m) mx = fmaxf(mx, p_lds[m]);
        float e[NM], se = 0.f;
        #pragma unroll
        for (int m = 0; m < NM; ++m) { e[m] = expf(p_lds[m] - mx); se += e[m]; }
        const float inv = 1.f / se;
        #pragma unroll
        for (int m = 0; m < NM; ++m) stats[m] = e[m] * inv + EPSF;
        // sigma = softplus + eps (stable softplus)
        #pragma unroll
        for (int m = 0; m < NM; ++m) {
            const float x = p_lds[NM + m];
            stats[NM + m] = fmaxf(x, 0.f) + log1pf(expf(-fabsf(x))) + EPSF;
        }
        // mu = mu_prev + softplus(Delta_hat)
        #pragma unroll
        for (int m = 0; m < NM; ++m) {
            const float x = p_lds[2 * NM + m];
            stats[2 * NM + m] = mu_prev[b * NM + m] + fmaxf(x, 0.f) + log1pf(expf(-fabsf(x)));
        }
    }
    __syncthreads();

    float w[NM], inv_sig[NM], mu[NM];
    #pragma unroll
    for (int m = 0; m < NM; ++m) {
        w[m]       = stats[m];
        inv_sig[m] = 1.f / stats[NM + m];      // sigma > 0 guaranteed
        mu[m]      = stats[2 * NM + m];
    }

    const unsigned char* mrow = mask + (size_t)b * TENC;
    float* arow = alpha_out + (size_t)b * TENC;
    for (int t = tid; t < TENC; t += 256) {
        const float jA = (float)t + 0.5f;
        const float jB = (float)t + 1.5f;
        float FA = 0.f, FB = 0.f;
        #pragma unroll
        for (int m = 0; m < NM; ++m) {
            const float zA = (mu[m] - jA) * inv_sig[m];
            const float zB = (mu[m] - jB) * inv_sig[m];
            const float sA = 1.f / (1.f + expf(-zA));   // sigmoid(zA)
            const float sB = 1.f / (1.f + expf(-zB));
            FA += w[m] / (1.f + sA);
            FB += w[m] / (1.f + sB);
        }
        float a = FB - FA;
        if (a == 0.f) a = EPSF;       // where(alpha==0, EPS, alpha)
        if (mrow[t])  a = 0.f;        // where(mask, 0, alpha)
        arow[t] = a;
    }
}

// ---------------------------------------------------------------------------
// Kernel 2: context[b,d] = sum_t alpha[b,t] * memory[b,t,d]
// Grid = B * SSPLIT blocks; each block owns a contiguous 64-row T-chunk
// (128 KB of memory), float4-coalesced, accumulates in registers, then
// 4 native f32 atomics into the pre-zeroed context region of d_out.
// ---------------------------------------------------------------------------
__global__ __launch_bounds__(256) void mol_context(
    const float* __restrict__ alpha,    // B x T
    const float* __restrict__ memory,   // B x T x D
    float* __restrict__ context)        // B x D (zeroed before launch)
{
    __shared__ float a_lds[TCH];

    const int b   = blockIdx.x >> 4;    // / SSPLIT
    const int s   = blockIdx.x & (SSPLIT - 1);
    const int tid = threadIdx.x;
    const int t0  = s * TCH;

    if (tid < TCH) a_lds[tid] = alpha[(size_t)b * TENC + t0 + tid];
    __syncthreads();

    const int dd = tid & 127;           // float4 column 0..127
    const int tt = tid >> 7;            // 0..1: two t-rows in flight per iter
    const float4* mem4 = (const float4*)(memory + ((size_t)b * TENC + t0) * DENC);

    float4 acc = make_float4(0.f, 0.f, 0.f, 0.f);
    #pragma unroll 8
    for (int t = tt; t < TCH; t += 2) {
        const float  a  = a_lds[t];                 // wave-broadcast, conflict-free
        const float4 mv = mem4[(size_t)t * 128 + dd];
        acc.x = fmaf(a, mv.x, acc.x);
        acc.y = fmaf(a, mv.y, acc.y);
        acc.z = fmaf(a, mv.z, acc.z);
        acc.w = fmaf(a, mv.w, acc.w);
    }

    float* ctx = context + (size_t)b * DENC + dd * 4;
    unsafeAtomicAdd(ctx + 0, acc.x);   // global_atomic_add_f32, 32 updates/addr
    unsafeAtomicAdd(ctx + 1, acc.y);
    unsafeAtomicAdd(ctx + 2, acc.z);
    unsafeAtomicAdd(ctx + 3, acc.w);
}

extern "C" void kernel_launch(void* const* d_in, const int* in_sizes, int n_in,
                              void* d_out, int out_size, void* d_ws, size_t ws_size,
                              hipStream_t stream) {
    const float*         q       = (const float*)d_in[0];          // att_rnn_h (64,1024)
    const float*         memory  = (const float*)d_in[1];          // (64,1024,512)
    const unsigned char* mask    = (const unsigned char*)d_in[2];  // bool (64,1024)
    const float*         mu_prev = (const float*)d_in[3];          // (64,5)
    const float*         W1      = (const float*)d_in[4];          // (1024,256)
    const float*         b1      = (const float*)d_in[5];          // (256,)
    const float*         W2      = (const float*)d_in[6];          // (256,15)
    const float*         b2      = (const float*)d_in[7];          // (15,)

    float* out   = (float*)d_out;
    float* ctx   = out;                  // context: first 64*512 floats
    float* alpha = out + NB * DENC;      // alpha_t: next 64*1024 floats

    // d_out is re-poisoned to 0xAA before every timed call; context is
    // atomically accumulated, so zero it first (memset node is capturable).
    hipMemsetAsync(ctx, 0, (size_t)NB * DENC * sizeof(float), stream);

    mol_front<<<NB, 256, 0, stream>>>(q, W1, b1, W2, b2, mu_prev, mask, alpha);
    mol_context<<<NB * SSPLIT, 256, 0, stream>>>(alpha, memory, ctx);
}

// Round 2
// 251.309 us; speedup vs baseline: 1.0412x; 1.0412x over previous
//
#include <hip/hip_runtime.h>
#include <cmath>

#define NB    64
#define TENC  1024
#define DENC  512
#define QDIM  1024
#define HDIM  256
#define NM    5
#define EPSF  1e-5f
#define SSPLIT 16
#define TCH   (TENC / SSPLIT)   // 64 t-rows per context block

// ---------------------------------------------------------------------------
// Kernel 1: per-batch front end (h -> params -> stats -> alpha).
// One block per batch row, 256 threads. ~1 MB of W1 per block (L2-resident).
// ---------------------------------------------------------------------------
__global__ __launch_bounds__(256) void mol_front(
    const float* __restrict__ q,        // B x 1024
    const float* __restrict__ W1,       // 1024 x 256 (row-major)
    const float* __restrict__ b1,       // 256
    const float* __restrict__ W2,       // 256 x 15
    const float* __restrict__ b2,       // 15
    const float* __restrict__ mu_prev,  // B x 5
    const unsigned char* __restrict__ mask, // B x 1024 (bool, 1 byte)
    float* __restrict__ alpha_out)      // B x 1024
{
    __shared__ float  q_lds[QDIM];
    __shared__ float4 part[4][64];      // split-K partials for h
    __shared__ float  h_lds[HDIM];
    __shared__ float  p_part[15][16];   // split-K partials for params
    __shared__ float  p_lds[16];
    __shared__ float  stats[16];        // w[5], sigma[5], mu[5]

    const int b   = blockIdx.x;
    const int tid = threadIdx.x;

    // stage q row (4 KB) into LDS, float4-coalesced
    ((float4*)q_lds)[tid] = ((const float4*)(q + (size_t)b * QDIM))[tid];
    __syncthreads();

    // h = relu(q @ W1 + b1): thread = (g = k-group 0..3, c = output float4 0..63)
    const int g = tid >> 6;
    const int c = tid & 63;
    {
        const float4* W1v = (const float4*)W1;   // [k][64] float4
        float4 acc = make_float4(0.f, 0.f, 0.f, 0.f);
        const int k0 = g << 8;
        #pragma unroll 4
        for (int k = 0; k < 256; ++k) {
            const float  qk = q_lds[k0 + k];                    // wave-broadcast
            const float4 wv = W1v[(size_t)(k0 + k) * 64 + c];   // 1KB/wave coalesced
            acc.x = fmaf(qk, wv.x, acc.x);
            acc.y = fmaf(qk, wv.y, acc.y);
            acc.z = fmaf(qk, wv.z, acc.z);
            acc.w = fmaf(qk, wv.w, acc.w);
        }
        part[g][c] = acc;
    }
    __syncthreads();

    if (tid < 64) {
        const float4 s0 = part[0][tid], s1 = part[1][tid];
        const float4 s2 = part[2][tid], s3 = part[3][tid];
        const float4 bb = ((const float4*)b1)[tid];
        float4 h;
        h.x = fmaxf(s0.x + s1.x + s2.x + s3.x + bb.x, 0.f);
        h.y = fmaxf(s0.y + s1.y + s2.y + s3.y + bb.y, 0.f);
        h.z = fmaxf(s0.z + s1.z + s2.z + s3.z + bb.z, 0.f);
        h.w = fmaxf(s0.w + s1.w + s2.w + s3.w + bb.w, 0.f);
        ((float4*)h_lds)[tid] = h;
    }
    __syncthreads();

    // params = h @ W2 + b2 : 15 outputs x 16 k-groups of 16 (240 threads)
    if (tid < 240) {
        const int o  = tid >> 4;        // output 0..14
        const int kg = tid & 15;        // k-group 0..15
        float acc = 0.f;
        #pragma unroll
        for (int i = 0; i < 16; ++i) {
            const int k = kg * 16 + i;
            acc = fmaf(h_lds[k], W2[k * 15 + o], acc);
        }
        p_part[o][kg] = acc;
    }
    __syncthreads();
    if (tid < 15) {
        float acc = b2[tid];
        #pragma unroll
        for (int kg = 0; kg < 16; ++kg) acc += p_part[tid][kg];
        p_lds[tid] = acc;
    }
    __syncthreads();

    if (tid == 0) {
        // softmax over p[0:5]
        float mx = p_lds[0];
        #pragma unroll
        for (int m = 1; m < NM; ++m) mx = fmaxf(mx, p_lds[m]);
        float e[NM], se = 0.f;
        #pragma unroll
        for (int m = 0; m < NM; ++m) { e[m] = expf(p_lds[m] - mx); se += e[m]; }
        const float inv = 1.f / se;
        #pragma unroll
        for (int m = 0; m < NM; ++m) stats[m] = e[m] * inv + EPSF;
        // sigma = softplus + eps (stable softplus)
        #pragma unroll
        for (int m = 0; m < NM; ++m) {
            const float x = p_lds[NM + m];
            stats[NM + m] = fmaxf(x, 0.f) + log1pf(expf(-fabsf(x))) + EPSF;
        }
        // mu = mu_prev + softplus(Delta_hat)
        #pragma unroll
        for (int m = 0; m < NM; ++m) {
            const float x = p_lds[2 * NM + m];
            stats[2 * NM + m] = mu_prev[b * NM + m] + fmaxf(x, 0.f) + log1pf(expf(-fabsf(x)));
        }
    }
    __syncthreads();

    float w[NM], inv_sig[NM], mu[NM];
    #pragma unroll
    for (int m = 0; m < NM; ++m) {
        w[m]       = stats[m];
        inv_sig[m] = 1.f / stats[NM + m];      // sigma > 0 guaranteed
        mu[m]      = stats[2 * NM + m];
    }

    const unsigned char* mrow = mask + (size_t)b * TENC;
    float* arow = alpha_out + (size_t)b * TENC;
    #pragma unroll
    for (int i = 0; i < 4; ++i) {
        const int t = tid + i * 256;
        const float jA = (float)t + 0.5f;
        const float jB = (float)t + 1.5f;
        float FA = 0.f, FB = 0.f;
        #pragma unroll
        for (int m = 0; m < NM; ++m) {
            const float zA = (mu[m] - jA) * inv_sig[m];
            const float zB = (mu[m] - jB) * inv_sig[m];
            const float sA = 1.f / (1.f + expf(-zA));   // sigmoid
            const float sB = 1.f / (1.f + expf(-zB));
            FA += w[m] / (1.f + sA);
            FB += w[m] / (1.f + sB);
        }
        float a = FB - FA;
        if (a == 0.f) a = EPSF;       // where(alpha==0, EPS, alpha)
        if (mrow[t])  a = 0.f;        // where(mask, 0, alpha)
        arow[t] = a;
    }
}

// ---------------------------------------------------------------------------
// Kernel 2: split-K partial context into d_ws (no atomics, no pre-memset).
// partial[s][b][d] : SSPLIT x NB x DENC floats = 2 MB.
// Grid = B * SSPLIT blocks; each block owns a contiguous 64-row T-chunk
// (128 KB of memory), float4-coalesced streaming loads.
// ---------------------------------------------------------------------------
__global__ __launch_bounds__(256) void mol_context(
    const float* __restrict__ alpha,    // B x T
    const float* __restrict__ memory,   // B x T x D
    float* __restrict__ partial)        // SSPLIT x B x DENC
{
    __shared__ float  a_lds[TCH];
    __shared__ float4 red[128];

    const int b   = blockIdx.x >> 4;    // / SSPLIT
    const int s   = blockIdx.x & (SSPLIT - 1);
    const int tid = threadIdx.x;
    const int t0  = s * TCH;

    if (tid < TCH) a_lds[tid] = alpha[(size_t)b * TENC + t0 + tid];
    __syncthreads();

    const int dd = tid & 127;           // float4 column 0..127
    const int tt = tid >> 7;            // 0..1: two t-rows in flight per iter
    const float4* mem4 = (const float4*)(memory + ((size_t)b * TENC + t0) * DENC);

    float4 acc = make_float4(0.f, 0.f, 0.f, 0.f);
    #pragma unroll 8
    for (int t = tt; t < TCH; t += 2) {
        const float  a  = a_lds[t];                 // wave-broadcast, conflict-free
        const float4 mv = mem4[(size_t)t * 128 + dd];
        acc.x = fmaf(a, mv.x, acc.x);
        acc.y = fmaf(a, mv.y, acc.y);
        acc.z = fmaf(a, mv.z, acc.z);
        acc.w = fmaf(a, mv.w, acc.w);
    }

    // combine the tt=0/tt=1 halves in LDS, then one coalesced float4 store
    if (tt == 1) red[dd] = acc;
    __syncthreads();
    if (tt == 0) {
        const float4 o = red[dd];
        acc.x += o.x; acc.y += o.y; acc.z += o.z; acc.w += o.w;
        ((float4*)(partial + ((size_t)s * NB + b) * DENC))[dd] = acc;
    }
}

// ---------------------------------------------------------------------------
// Kernel 3: context[b][d] = sum_s partial[s][b][d]. 32 blocks x 256 thr,
// one float4 output per thread, 16 strided-but-coalesced float4 loads.
// ---------------------------------------------------------------------------
__global__ __launch_bounds__(256) void mol_reduce(
    const float* __restrict__ partial,  // SSPLIT x B x DENC
    float* __restrict__ context)        // B x DENC
{
    const int idx = blockIdx.x * 256 + threadIdx.x;   // 0..8191 float4s
    const float4* p4 = (const float4*)partial;
    float4 acc = p4[idx];
    #pragma unroll
    for (int s = 1; s < SSPLIT; ++s) {
        const float4 v = p4[(size_t)s * (NB * DENC / 4) + idx];
        acc.x += v.x; acc.y += v.y; acc.z += v.z; acc.w += v.w;
    }
    ((float4*)context)[idx] = acc;
}

extern "C" void kernel_launch(void* const* d_in, const int* in_sizes, int n_in,
                              void* d_out, int out_size, void* d_ws, size_t ws_size,
                              hipStream_t stream) {
    const float*         q       = (const float*)d_in[0];          // att_rnn_h (64,1024)
    const float*         memory  = (const float*)d_in[1];          // (64,1024,512)
    const unsigned char* mask    = (const unsigned char*)d_in[2];  // bool (64,1024)
    const float*         mu_prev = (const float*)d_in[3];          // (64,5)
    const float*         W1      = (const float*)d_in[4];          // (1024,256)
    const float*         b1      = (const float*)d_in[5];          // (256,)
    const float*         W2      = (const float*)d_in[6];          // (256,15)
    const float*         b2      = (const float*)d_in[7];          // (15,)

    float* out   = (float*)d_out;
    float* ctx   = out;                  // context: first 64*512 floats
    float* alpha = out + NB * DENC;      // alpha_t: next 64*1024 floats
    float* part  = (float*)d_ws;         // SSPLIT*NB*DENC floats = 2 MB scratch

    mol_front<<<NB, 256, 0, stream>>>(q, W1, b1, W2, b2, mu_prev, mask, alpha);
    mol_context<<<NB * SSPLIT, 256, 0, stream>>>(alpha, memory, part);
    mol_reduce<<<NB * DENC / 4 / 256, 256, 0, stream>>>(part, ctx);
}